// Round 5
// baseline (603.733 us; speedup 1.0000x reference)
//
#include <hip/hip_runtime.h>
#include <hip/hip_bf16.h>
#include <math.h>

#define NB 4
#define NS 4096
#define NE 1024
#define ND 64

typedef short bf16x8 __attribute__((ext_vector_type(8)));
typedef float f32x4  __attribute__((ext_vector_type(4)));

static __device__ inline unsigned short f2bf(float f) {
    __hip_bfloat16 h = __float2bfloat16(f);
    return *reinterpret_cast<unsigned short*>(&h);
}

// ---------------- prep: W fp32->bf16 (Wq pre-scaled 1/8) + mask dtype detect --
// grid 97 blocks: 0..95 convert W (z = b>>5, chunk = b&31), block 96 detects.
__global__ void prep_kernel(const float* __restrict__ Wq, const float* __restrict__ Wk,
                            const float* __restrict__ Wv, unsigned short* __restrict__ Wb,
                            const unsigned int* __restrict__ mw, int* __restrict__ flag) {
    if (blockIdx.x == 96) {
        // u8 bool mask: 32-bit words over random 0/1 bytes exceed 1 almost surely.
        __shared__ int found;
        if (threadIdx.x == 0) found = 0;
        __syncthreads();
        int f = 0;
        for (int i = threadIdx.x; i < 4096; i += 256)
            if (mw[i] > 1u) f = 1;
        if (f) atomicOr(&found, 1);
        __syncthreads();
        if (threadIdx.x == 0) *flag = found;   // 1 => u8 bool, 0 => int32
        return;
    }
    const int z = blockIdx.x >> 5;
    const int chunk = blockIdx.x & 31;
    const float* W = (z == 0) ? Wq : (z == 1) ? Wk : Wv;
    unsigned short* o = Wb + (size_t)z * (ND * NE);
    const float scale = (z == 0) ? 0.125f : 1.0f;
    int i0 = chunk * 2048 + threadIdx.x * 8;
    float4 a = *(const float4*)&W[i0];
    float4 b = *(const float4*)&W[i0 + 4];
    ushort4 u0 = { f2bf(a.x * scale), f2bf(a.y * scale), f2bf(a.z * scale), f2bf(a.w * scale) };
    ushort4 u1 = { f2bf(b.x * scale), f2bf(b.y * scale), f2bf(b.z * scale), f2bf(b.w * scale) };
    *(ushort4*)&o[i0]     = u0;
    *(ushort4*)&o[i0 + 4] = u1;
}

// ---------------- projection (LDS-staged A, bf16 MFMA) ----------------
// Y[m][d] = sum_e X[m][e] * W[d][e]. grid (M/64, 3), block 256 = 4 waves;
// wave owns 16 rows. X staged via coalesced float4 -> bf16 LDS (stride 72
// shorts: 2-way bank alias = free); W B-frags direct global (L2-hot).
__global__ __launch_bounds__(256) void proj_kernel(
    const float* __restrict__ Xq, const float* __restrict__ Xk, const float* __restrict__ Xv,
    const unsigned short* __restrict__ Wb,
    unsigned short* __restrict__ Qp, unsigned short* __restrict__ Kp,
    unsigned short* __restrict__ Vtp)
{
    __shared__ short Xs[64][72];

    const int z = blockIdx.y;
    const float* X = (z == 0) ? Xq : (z == 1) ? Xk : Xv;
    const unsigned short* W = Wb + (size_t)z * (ND * NE);

    const int t    = threadIdx.x;
    const int wv   = t >> 6;
    const int lane = t & 63;
    const int quad = lane >> 4;
    const int l16  = lane & 15;
    const int m0   = blockIdx.x * 64;

    f32x4 acc[4] = {};   // acc[nt][r]: row m0+wv*16+quad*4+r, col nt*16+l16

    for (int e0 = 0; e0 < NE; e0 += 64) {
        __syncthreads();
        #pragma unroll
        for (int i = 0; i < 4; ++i) {           // 64 rows x 16 float4, coalesced
            int idx = t + i * 256;
            int row = idx >> 4, c4 = (idx & 15) * 4;
            float4 v = *(const float4*)&X[(size_t)(m0 + row) * NE + e0 + c4];
            short4 s = { (short)f2bf(v.x), (short)f2bf(v.y),
                         (short)f2bf(v.z), (short)f2bf(v.w) };
            *(short4*)&Xs[row][c4] = s;
        }
        __syncthreads();
        bf16x8 a0 = *(const bf16x8*)&Xs[wv * 16 + l16][quad * 8];
        bf16x8 a1 = *(const bf16x8*)&Xs[wv * 16 + l16][32 + quad * 8];
        #pragma unroll
        for (int nt = 0; nt < 4; ++nt) {
            const unsigned short* Wr = W + (size_t)(nt * 16 + l16) * NE + e0 + quad * 8;
            bf16x8 b0 = *(const bf16x8*)&Wr[0];
            bf16x8 b1 = *(const bf16x8*)&Wr[32];
            acc[nt] = __builtin_amdgcn_mfma_f32_16x16x32_bf16(a0, b0, acc[nt], 0, 0, 0);
            acc[nt] = __builtin_amdgcn_mfma_f32_16x16x32_bf16(a1, b1, acc[nt], 0, 0, 0);
        }
    }

    #pragma unroll
    for (int nt = 0; nt < 4; ++nt)
        #pragma unroll
        for (int r = 0; r < 4; ++r) {
            int m   = m0 + wv * 16 + quad * 4 + r;
            int col = nt * 16 + l16;
            unsigned short u = f2bf(acc[nt][r]);
            if (z == 0)      Qp[(size_t)m * ND + col] = u;
            else if (z == 1) Kp[(size_t)m * ND + col] = u;
            else             Vtp[((size_t)(m >> 12) * ND + col) * NS + (m & 4095)] = u;
        }
}

// ---------------- flash attention (no-max softmax, in-block split-K x4) -----
// grid (NS/16, B), block 256 = 4 waves over the SAME 16 q-rows; wave w owns
// keys [w*1024, w*1024+1024) in 16 tiles of 64. Mask staged per tile as one
// coalesced uint4/lane into wave-private LDS. Two barriers/tile order the
// wave-private LDS round-trips (round-3 lesson). Split-K merge via LDS
// atomicAdd into a union over the tile buffers (LDS ~14.4 KB).
#define SS(w,r,c) Ss[(((w) * 16 + (r)) * 72) + (c)]
#define MS(w,r,c) Ms[(((w) * 16 + (r)) * 80) + (c)]
#define OP(r,c)   Op[((r) * 68) + (c)]
__global__ __launch_bounds__(256, 5) void attn_kernel(
    const unsigned short* __restrict__ Qp, const unsigned short* __restrict__ Kp,
    const unsigned short* __restrict__ Vtp,
    const void* __restrict__ maskp, const int* __restrict__ flagp,
    float* __restrict__ out)
{
    __shared__ uint4 smem4[904];                 // 14464 B, 16-B aligned
    char* smem = (char*)smem4;
    short* Ss = (short*)smem;                    // [4][16][72] shorts = 9216 B
    unsigned char* Ms = (unsigned char*)(smem + 9216);   // [4][16][80]   = 5120 B
    float* Op = (float*)smem;                    // [16][68] f32 = 4352 B (union)
    float* Lr = (float*)(smem + 14336);          // [16] f32

    const int t    = threadIdx.x;
    const int wv   = t >> 6;
    const int lane = t & 63;
    const int quad = lane >> 4;
    const int l16  = lane & 15;
    const int b    = blockIdx.y;
    const int q0   = blockIdx.x * 16;
    const int koff = wv * 1024;

    const bool m_u8 = (*flagp != 0);
    const unsigned char* m8  = (const unsigned char*)maskp;
    const int*           m32 = (const int*)maskp;

    // Q A-fragments (pre-scaled 1/8): A[m=l16][k=quad*8+j]
    const unsigned short* Qrow = Qp + ((size_t)b * NS + q0 + l16) * ND;
    const bf16x8 qf0 = *(const bf16x8*)&Qrow[quad * 8];
    const bf16x8 qf1 = *(const bf16x8*)&Qrow[32 + quad * 8];

    const unsigned short* Kbase = Kp  + ((size_t)b * NS) * ND;
    const unsigned short* Vbase = Vtp + (size_t)b * ND * NS;

    // mask staging coords: lane covers row lane>>2, 16 cols at (lane&3)*16
    const int mrow = lane >> 2;
    const int mc16 = (lane & 3) * 16;

    float l_lane[4] = {};
    f32x4 Oacc[4] = {};   // Oacc[nt][r]: row q0+quad*4+r, col nt*16+l16

    for (int it = 0; it < 16; ++it) {
        const int k0 = koff + it * 64;

        // ---- stage mask tile (wave-private): 16 rows x 64 cols as bytes ----
        if (m_u8) {
            uint4 mval = *(const uint4*)&m8[((size_t)b * NS + q0 + mrow) * NS + k0 + mc16];
            *(uint4*)&MS(wv, mrow, mc16) = mval;
        } else {
            const int* mp = &m32[((size_t)b * NS + q0 + mrow) * NS + k0 + mc16];
            unsigned int w[4] = {0, 0, 0, 0};
            #pragma unroll
            for (int j = 0; j < 16; ++j)
                w[j >> 2] |= (mp[j] ? 1u : 0u) << ((j & 3) * 8);
            uint4 pk = { w[0], w[1], w[2], w[3] };
            *(uint4*)&MS(wv, mrow, mc16) = pk;
        }

        // ---- QK^T: S[q=quad*4+r][key=kt*16+l16] ----
        f32x4 sc[4] = {};
        #pragma unroll
        for (int kt = 0; kt < 4; ++kt) {
            const unsigned short* Krow = Kbase + (size_t)(k0 + kt * 16 + l16) * ND;
            bf16x8 kf0 = *(const bf16x8*)&Krow[quad * 8];
            bf16x8 kf1 = *(const bf16x8*)&Krow[32 + quad * 8];
            sc[kt] = __builtin_amdgcn_mfma_f32_16x16x32_bf16(qf0, kf0, sc[kt], 0, 0, 0);
            sc[kt] = __builtin_amdgcn_mfma_f32_16x16x32_bf16(qf1, kf1, sc[kt], 0, 0, 0);
        }

        __syncthreads();   // order mask write -> read; P(prev) read -> P write

        // ---- p = exp(s) (|s| <~ 2.5), masked -> 0; P -> LDS bf16 ----
        #pragma unroll
        for (int kt = 0; kt < 4; ++kt)
            #pragma unroll
            for (int r = 0; r < 4; ++r) {
                unsigned char mb = MS(wv, quad * 4 + r, kt * 16 + l16);
                float p = mb ? 0.0f : __expf(sc[kt][r]);
                l_lane[r] += p;
                SS(wv, quad * 4 + r, kt * 16 + l16) = (short)f2bf(p);
            }

        __syncthreads();   // order P write -> read

        // ---- PV: A = P from LDS, B = Vt[d][k] direct global ----
        bf16x8 a0 = *(const bf16x8*)&SS(wv, l16, quad * 8);
        bf16x8 a1 = *(const bf16x8*)&SS(wv, l16, 32 + quad * 8);
        #pragma unroll
        for (int nt = 0; nt < 4; ++nt) {
            const unsigned short* Vrow = Vbase + (size_t)(nt * 16 + l16) * NS + k0;
            bf16x8 vf0 = *(const bf16x8*)&Vrow[quad * 8];
            bf16x8 vf1 = *(const bf16x8*)&Vrow[32 + quad * 8];
            Oacc[nt] = __builtin_amdgcn_mfma_f32_16x16x32_bf16(a0, vf0, Oacc[nt], 0, 0, 0);
            Oacc[nt] = __builtin_amdgcn_mfma_f32_16x16x32_bf16(a1, vf1, Oacc[nt], 0, 0, 0);
        }
    }

    // l: reduce across the 16 lanes of each row group
    #pragma unroll
    for (int r = 0; r < 4; ++r) {
        #pragma unroll
        for (int off = 1; off < 16; off <<= 1)
            l_lane[r] += __shfl_xor(l_lane[r], off);
    }

    // ---- split-K merge via LDS atomics (Op unions over Ss/Ms region) ----
    __syncthreads();                             // all waves done with Ss/Ms
    for (int i = t; i < 16 * 68; i += 256) Op[i] = 0.0f;
    if (t < 16) Lr[t] = 0.0f;
    __syncthreads();
    #pragma unroll
    for (int nt = 0; nt < 4; ++nt)
        #pragma unroll
        for (int r = 0; r < 4; ++r)
            atomicAdd(&OP(quad * 4 + r, nt * 16 + l16), Oacc[nt][r]);
    if (l16 == 0) {
        #pragma unroll
        for (int r = 0; r < 4; ++r)
            atomicAdd(&Lr[quad * 4 + r], l_lane[r]);
    }
    __syncthreads();

    // thread t writes float4 at (q = t>>4, d = (t&15)*4)
    {
        int q  = t >> 4;
        int d4 = (t & 15) * 4;
        f32x4 s = *(const f32x4*)&OP(q, d4);
        float inv = 1.0f / Lr[q];
        float4 o = { s[0] * inv, s[1] * inv, s[2] * inv, s[3] * inv };
        *(float4*)&out[((size_t)b * NS + q0 + q) * ND + d4] = o;
    }
}

extern "C" void kernel_launch(void* const* d_in, const int* in_sizes, int n_in,
                              void* d_out, int out_size, void* d_ws, size_t ws_size,
                              hipStream_t stream) {
    const float* queries = (const float*)d_in[0];
    const float* keys    = (const float*)d_in[1];
    const float* values  = (const float*)d_in[2];
    const void*  mask    = d_in[3];
    const float* Wq      = (const float*)d_in[4];
    const float* Wk      = (const float*)d_in[5];
    const float* Wv      = (const float*)d_in[6];
    float* out = (float*)d_out;

    char* ws = (char*)d_ws;
    int* flag = (int*)ws;
    unsigned short* Wb = (unsigned short*)(ws + 256);               // 384 KiB
    size_t wb = (size_t)3 * ND * NE * sizeof(unsigned short);
    size_t pb = (size_t)NB * NS * ND * sizeof(unsigned short);      // 2 MiB each
    unsigned short* Qp  = (unsigned short*)(ws + 256 + wb);
    unsigned short* Kp  = (unsigned short*)(ws + 256 + wb + pb);
    unsigned short* Vtp = (unsigned short*)(ws + 256 + wb + 2 * pb);

    hipLaunchKernelGGL(prep_kernel, dim3(97), dim3(256), 0, stream,
                       Wq, Wk, Wv, Wb, (const unsigned int*)mask, flag);
    hipLaunchKernelGGL(proj_kernel, dim3((NB * NS) / 64, 3), dim3(256), 0, stream,
                       queries, keys, values, Wb, Qp, Kp, Vtp);
    hipLaunchKernelGGL(attn_kernel, dim3(NS / 16, NB), dim3(256), 0, stream,
                       Qp, Kp, Vtp, mask, flag, out);
}